// Round 9
// baseline (162.334 us; speedup 1.0000x reference)
//
#include <hip/hip_runtime.h>

#define IN_DIM 256
#define HD 256        // H*D
#define NHEAD 4
#define BM 128        // rows per block in gemm

typedef __attribute__((ext_vector_type(8))) short short8;
typedef __attribute__((ext_vector_type(4))) float f32x4;

__device__ __forceinline__ float bf2f(ushort u) {
    unsigned x = ((unsigned)u) << 16;
    float f;
    __builtin_memcpy(&f, &x, 4);
    return f;
}
__device__ __forceinline__ ushort f2bf(float f) {
    unsigned x;
    __builtin_memcpy(&x, &f, 4);
    unsigned r = (x + 0x7FFFu + ((x >> 16) & 1u)) >> 16;   // RNE
    return (ushort)r;
}
__device__ __forceinline__ short8 cvt8(float4 x, float4 y) {
    short8 a;
    a[0] = (short)f2bf(x.x); a[1] = (short)f2bf(x.y);
    a[2] = (short)f2bf(x.z); a[3] = (short)f2bf(x.w);
    a[4] = (short)f2bf(y.x); a[5] = (short)f2bf(y.y);
    a[6] = (short)f2bf(y.z); a[7] = (short)f2bf(y.w);
    return a;
}

// ---------------------------------------------------------------- fallback (ws-too-small tripwire)
__global__ void fill_one(float* __restrict__ out, int n) {
    int i = blockIdx.x * 256 + threadIdx.x;
    if (i < n) out[i] = 1.0f;
}

// ---------------------------------------------------------------- K0: WT build + cnt/donecnt zero
__global__ void conv_w_zero(const float* __restrict__ W, ushort* __restrict__ WT,
                            int* __restrict__ cnt, int* __restrict__ donecnt, int n) {
    int idx = blockIdx.x * 256 + threadIdx.x;   // 65536 threads
    int k = idx >> 8, c = idx & 255;
    WT[c * 256 + k] = f2bf(W[idx]);
    for (int i = idx; i < n; i += 65536) cnt[i] = 0;
    if (idx == 0) *donecnt = 0;
}

// ---------------------------------------------------------------- K1: gemm (BM=128) + in-block hist tail
// MFMA 16x16x32 bf16 fragment layout (m92-verified):
//   A lane l -> row l&15, k=(l>>4)*8..+7 ; B lane l -> col l&15, same k packing
//   D lane l -> col l&15, row (l>>4)*4 + reg
// hist: after epilogue, all blocks grid-stride 4-edge granules (no separate
// hist blocks -> no 32KB-LDS over-reservation throttling hist occupancy)
__global__ __launch_bounds__(256, 2) void gemm_hist(const float* __restrict__ h,
                                                    const short* __restrict__ WT,
                                                    ushort* __restrict__ featb,
                                                    float* __restrict__ el,
                                                    float* __restrict__ er,
                                                    const float* __restrict__ attn_l,
                                                    const float* __restrict__ attn_r,
                                                    const int* __restrict__ dst,
                                                    int* __restrict__ cnt,
                                                    int* __restrict__ epos,
                                                    int n, int e4, int e) {
    __shared__ __align__(16) ushort blds[2][8192];   // 2 x 16 KB
    int t = threadIdx.x;
    int w = t >> 6, l = t & 63;
    int c15 = l & 15, g = l >> 4;
    int blockBase = blockIdx.x * BM;
    int row0 = blockBase + w * 32 + c15;
    int rA0 = row0 < n ? row0 : n - 1;
    int rA1 = (row0 + 16) < n ? (row0 + 16) : n - 1;
    const float* hA0 = h + (size_t)rA0 * 256 + g * 8;
    const float* hA1 = h + (size_t)rA1 * 256 + g * 8;

    f32x4 acc[2][16];
#pragma unroll
    for (int af = 0; af < 2; ++af)
#pragma unroll
        for (int ct = 0; ct < 16; ++ct) acc[af][ct] = (f32x4)(0.0f);

    short8 st[4];
    int sc[4], sb[4];
#pragma unroll
    for (int p = 0; p < 4; ++p) {
        int q = t + p * 256;
        sc[p] = q >> 2;
        int gg = q & 3;
        sb[p] = ((sc[p] * 64 + gg * 16) ^ ((sc[p] & 7) << 4));
    }

#pragma unroll
    for (int p = 0; p < 4; ++p)
        st[p] = *(const short8*)(WT + sc[p] * 256 + ((t + p * 256) & 3) * 8);
#pragma unroll
    for (int p = 0; p < 4; ++p)
        *(short8*)((char*)blds[0] + sb[p]) = st[p];
    __syncthreads();

    for (int kk = 0; kk < 8; ++kk) {
        int buf = kk & 1;
        if (kk < 7) {
#pragma unroll
            for (int p = 0; p < 4; ++p)
                st[p] = *(const short8*)(WT + sc[p] * 256 + (kk + 1) * 32 + ((t + p * 256) & 3) * 8);
        }
        float4 x0 = *(const float4*)(hA0 + kk * 32);
        float4 y0 = *(const float4*)(hA0 + kk * 32 + 4);
        float4 x1 = *(const float4*)(hA1 + kk * 32);
        float4 y1 = *(const float4*)(hA1 + kk * 32 + 4);
        short8 a0 = cvt8(x0, y0);
        short8 a1 = cvt8(x1, y1);
        const char* bb = (const char*)blds[buf];
#pragma unroll
        for (int ct = 0; ct < 16; ++ct) {
            int c = ct * 16 + c15;
            short8 bv = *(const short8*)(bb + ((c * 64 + g * 16) ^ ((c & 7) << 4)));
            acc[0][ct] = __builtin_amdgcn_mfma_f32_16x16x32_bf16(a0, bv, acc[0][ct], 0, 0, 0);
            acc[1][ct] = __builtin_amdgcn_mfma_f32_16x16x32_bf16(a1, bv, acc[1][ct], 0, 0, 0);
        }
        if (kk < 7) {
#pragma unroll
            for (int p = 0; p < 4; ++p)
                *(short8*)((char*)blds[buf ^ 1] + sb[p]) = st[p];
        }
        __syncthreads();
    }

    float alv[16], arv[16];
#pragma unroll
    for (int ct = 0; ct < 16; ++ct) {
        alv[ct] = attn_l[ct * 16 + c15];
        arv[ct] = attn_r[ct * 16 + c15];
    }

#pragma unroll
    for (int af = 0; af < 2; ++af) {
        int rowb = blockBase + w * 32 + af * 16 + g * 4;
#pragma unroll
        for (int r = 0; r < 4; ++r) {
            int row = rowb + r;
            if (row < n) {
#pragma unroll
                for (int ct = 0; ct < 16; ++ct)
                    featb[(size_t)row * 256 + ct * 16 + c15] = f2bf(acc[af][ct][r]);
            }
            float pl[4] = {0.f, 0.f, 0.f, 0.f}, pr[4] = {0.f, 0.f, 0.f, 0.f};
#pragma unroll
            for (int ct = 0; ct < 16; ++ct) {
                pl[ct >> 2] += acc[af][ct][r] * alv[ct];
                pr[ct >> 2] += acc[af][ct][r] * arv[ct];
            }
#pragma unroll
            for (int m = 1; m < 16; m <<= 1) {
#pragma unroll
                for (int hh = 0; hh < 4; ++hh) {
                    pl[hh] += __shfl_xor(pl[hh], m, 64);
                    pr[hh] += __shfl_xor(pr[hh], m, 64);
                }
            }
            if (row < n) {
                if (c15 < 4)       el[row * 4 + c15]       = pl[c15];
                else if (c15 < 8)  er[row * 4 + (c15 - 4)] = pr[c15 - 4];
            }
        }
    }

    // ---------------- hist tail: grid-stride 4-edge granules ----------------
    int nthreads = gridDim.x * 256;
    for (int qq = blockIdx.x * 256 + t; qq < e4; qq += nthreads) {
        int base = qq * 4;
        int4 d4 = *(const int4*)(dst + base);
        int4 p4;
        p4.x = atomicAdd(&cnt[d4.x], 1);
        p4.y = atomicAdd(&cnt[d4.y], 1);
        p4.z = atomicAdd(&cnt[d4.z], 1);
        p4.w = atomicAdd(&cnt[d4.w], 1);
        *(int4*)(epos + base) = p4;
    }
    if (blockIdx.x == 0 && t == 0) {
        for (int q = e4 * 4; q < e; ++q) epos[q] = atomicAdd(&cnt[dst[q]], 1);
    }
}

// ---------------------------------------------------------------- K2: fused two-level scan (last-block pattern)
__global__ __launch_bounds__(1024) void scan_fused(const int* __restrict__ cnt,
                                                   int* __restrict__ rl,
                                                   int* __restrict__ bsum,
                                                   int* __restrict__ donecnt,
                                                   int n, int nb) {
    __shared__ int wsums[16];
    __shared__ int isLast;
    int t = threadIdx.x, lane = t & 63, wid = t >> 6;
    int i = blockIdx.x * 1024 + t;
    int x = (i < n) ? cnt[i] : 0;
    int s = x;
#pragma unroll
    for (int off = 1; off < 64; off <<= 1) {
        int v = __shfl_up(s, off, 64);
        if (lane >= off) s += v;
    }
    if (lane == 63) wsums[wid] = s;
    __syncthreads();
    if (wid == 0) {
        int ws = (lane < 16) ? wsums[lane] : 0;
#pragma unroll
        for (int off = 1; off < 16; off <<= 1) {
            int v = __shfl_up(ws, off, 64);
            if (lane >= off) ws += v;
        }
        if (lane < 16) wsums[lane] = ws;
    }
    __syncthreads();
    int woff = (wid > 0) ? wsums[wid - 1] : 0;
    if (i <= n) rl[i] = woff + s - x;
    if (t == 1023) bsum[blockIdx.x] = wsums[15];

    // last block to finish scans bsum (exclusive, in place)
    __threadfence();
    if (t == 0) {
        int prev = atomicAdd(donecnt, 1);
        isLast = (prev == gridDim.x - 1) ? 1 : 0;
    }
    __syncthreads();
    if (!isLast) return;
    __threadfence();   // acquire: see all blocks' bsum writes
    int carry = 0;
    for (int base = 0; base < nb; base += 1024) {
        __syncthreads();
        int ii = base + t;
        int xx = (ii < nb) ? bsum[ii] : 0;
        int ss = xx;
#pragma unroll
        for (int off = 1; off < 64; off <<= 1) {
            int v = __shfl_up(ss, off, 64);
            if (lane >= off) ss += v;
        }
        if (lane == 63) wsums[wid] = ss;
        __syncthreads();
        if (wid == 0) {
            int ws = (lane < 16) ? wsums[lane] : 0;
#pragma unroll
            for (int off = 1; off < 16; off <<= 1) {
                int v = __shfl_up(ws, off, 64);
                if (lane >= off) ws += v;
            }
            if (lane < 16) wsums[lane] = ws;
        }
        __syncthreads();
        int woff2 = (wid > 0) ? wsums[wid - 1] : 0;
        if (ii < nb) bsum[ii] = carry + woff2 + ss - xx;
        int tot = wsums[15];
        carry += tot;
    }
}

// ---------------------------------------------------------------- K3: CSR fill — no atomic, grid-stride 4-edge granules
__global__ void fill_kernel(const int* __restrict__ src, const int* __restrict__ dst,
                            const int* __restrict__ rl, const int* __restrict__ boffs,
                            const int* __restrict__ epos,
                            int* __restrict__ esrc, int e4, int e) {
    int nthreads = gridDim.x * 256;
    for (int i = blockIdx.x * 256 + threadIdx.x; i < e4; i += nthreads) {
        int base = i * 4;
        int4 d4 = *(const int4*)(dst + base);
        int4 s4 = *(const int4*)(src + base);
        int4 p4 = *(const int4*)(epos + base);
        int pos0 = boffs[d4.x >> 10] + rl[d4.x] + p4.x;
        int pos1 = boffs[d4.y >> 10] + rl[d4.y] + p4.y;
        int pos2 = boffs[d4.z >> 10] + rl[d4.z] + p4.z;
        int pos3 = boffs[d4.w >> 10] + rl[d4.w] + p4.w;
        if (pos0 >= 0 && pos0 < e) esrc[pos0] = s4.x;
        if (pos1 >= 0 && pos1 < e) esrc[pos1] = s4.y;
        if (pos2 >= 0 && pos2 < e) esrc[pos2] = s4.z;
        if (pos3 >= 0 && pos3 < e) esrc[pos3] = s4.w;
    }
    if (blockIdx.x == 0 && threadIdx.x == 0) {
        for (int q = e4 * 4; q < e; ++q) {
            int d = dst[q];
            int pos = boffs[d >> 10] + rl[d] + epos[q];
            if (pos >= 0 && pos < e) esrc[pos] = src[q];
        }
    }
}

// ---------------------------------------------------------------- K4: per-dst aggregate, 1 wave/node (unchanged — at delivered-BW ceiling)
__global__ __launch_bounds__(64) void aggregate(const int* __restrict__ rl,
                                                const int* __restrict__ boffs,
                                                const int* __restrict__ esrc,
                                                const float* __restrict__ el,
                                                const float* __restrict__ er,
                                                const ushort* __restrict__ featb,
                                                const float* __restrict__ bias,
                                                float* __restrict__ out, int n) {
    __shared__ int sbuf[64];
    __shared__ float wbuf[64][4];
    int node = blockIdx.x;
    int l = threadIdx.x;
    int hh = l >> 4;
    int beg = boffs[node >> 10] + rl[node];
    int end = boffs[(node + 1) >> 10] + rl[node + 1];
    float4 bv = *(const float4*)(bias + l * 4);
    float* op = out + (size_t)node * 256 + l * 4;
    if (beg >= end) {
        float4 v;
        v.x = bv.x > 0.f ? bv.x : 0.01f * bv.x;
        v.y = bv.y > 0.f ? bv.y : 0.01f * bv.y;
        v.z = bv.z > 0.f ? bv.z : 0.01f * bv.z;
        v.w = bv.w > 0.f ? bv.w : 0.01f * bv.w;
        *(float4*)op = v;
        return;
    }
    float4 r4 = *(const float4*)(er + (size_t)node * 4);
    float ax = 0.f, ay = 0.f, az = 0.f, aw = 0.f, s = 0.f;
    for (int cb = beg; cb < end; cb += 64) {
        int cn = min(64, end - cb);
        __syncthreads();
        if (l < cn) {
            int sv = esrc[cb + l];
            sv = (sv >= 0 && sv < n) ? sv : 0;   // poison-proof
            sbuf[l] = sv;
            float4 l4 = *(const float4*)(el + (size_t)sv * 4);
            float e0 = l4.x + r4.x; e0 = e0 > 0.f ? e0 : 0.2f * e0;
            float e1 = l4.y + r4.y; e1 = e1 > 0.f ? e1 : 0.2f * e1;
            float e2 = l4.z + r4.z; e2 = e2 > 0.f ? e2 : 0.2f * e2;
            float e3 = l4.w + r4.w; e3 = e3 > 0.f ? e3 : 0.2f * e3;
            wbuf[l][0] = __expf(fminf(e0, 60.f));
            wbuf[l][1] = __expf(fminf(e1, 60.f));
            wbuf[l][2] = __expf(fminf(e2, 60.f));
            wbuf[l][3] = __expf(fminf(e3, 60.f));
        }
        __syncthreads();
#pragma unroll 4
        for (int j = 0; j < cn; ++j) {
            int sid = sbuf[j];
            float wgt = wbuf[j][hh];
            ushort4 f4 = *(const ushort4*)(featb + (size_t)sid * 256 + l * 4);
            ax += wgt * bf2f(f4.x);
            ay += wgt * bf2f(f4.y);
            az += wgt * bf2f(f4.z);
            aw += wgt * bf2f(f4.w);
            s += wgt;
        }
    }
    float inv = 1.f / fmaxf(s, 1e-9f);
    float4 v;
    v.x = ax * inv + bv.x; v.x = v.x > 0.f ? v.x : 0.01f * v.x;
    v.y = ay * inv + bv.y; v.y = v.y > 0.f ? v.y : 0.01f * v.y;
    v.z = az * inv + bv.z; v.z = v.z > 0.f ? v.z : 0.01f * v.z;
    v.w = aw * inv + bv.w; v.w = v.w > 0.f ? v.w : 0.01f * v.w;
    *(float4*)op = v;
}

// ----------------------------------------------------------------
extern "C" void kernel_launch(void* const* d_in, const int* in_sizes, int n_in,
                              void* d_out, int out_size, void* d_ws, size_t ws_size,
                              hipStream_t stream) {
    const float* h      = (const float*)d_in[0];
    const int*   src    = (const int*)d_in[1];
    const int*   dst    = (const int*)d_in[2];
    const float* W      = (const float*)d_in[3];
    const float* attn_l = (const float*)d_in[4];
    const float* attn_r = (const float*)d_in[5];
    const float* bias   = (const float*)d_in[6];
    float* out = (float*)d_out;

    int N = in_sizes[0] / IN_DIM;
    int E = in_sizes[1];
    int E4 = E / 4;
    int NB = (N + 1 + 1023) / 1024;

    auto al = [](size_t x) { return (x + 255) & ~(size_t)255; };
    char* ws = (char*)d_ws;
    size_t o = 0;
    ushort* featb = (ushort*)(ws + o); o += al((size_t)N * HD * 2);
    float*  el    = (float*)(ws + o);  o += al((size_t)N * NHEAD * 4);
    float*  er    = (float*)(ws + o);  o += al((size_t)N * NHEAD * 4);
    int*    rl    = (int*)(ws + o);    o += al((size_t)(N + 1) * 4);
    int*    cnt   = (int*)(ws + o);    o += al((size_t)N * 4);
    int*    bsum  = (int*)(ws + o);    o += al((size_t)NB * 4);
    int*    done  = (int*)(ws + o);    o += al(4);
    int*    esrc  = (int*)(ws + o);    o += al((size_t)E * 4);
    int*    epos  = (int*)(ws + o);    o += al((size_t)E * 4);
    ushort* WT    = (ushort*)(ws + o); o += al((size_t)IN_DIM * HD * 2);
    (void)n_in;

    if (ws_size < o) {
        fill_one<<<(out_size + 255) / 256, 256, 0, stream>>>(out, out_size);
        return;
    }

    // K0: WT build + cnt/done zero
    conv_w_zero<<<(IN_DIM * HD) / 256, 256, 0, stream>>>(W, WT, cnt, done, N);

    // K1: gemm + in-block hist tail
    int GB = (N + BM - 1) / BM;
    gemm_hist<<<GB, 256, 0, stream>>>(h, (const short*)WT, featb, el, er,
                                      attn_l, attn_r, dst, cnt, epos, N, E4, E);

    // K2: fused two-level scan
    scan_fused<<<NB, 1024, 0, stream>>>(cnt, rl, bsum, done, N, NB);

    // K3: CSR fill (no atomics), grid-stride
    int FB = (E4 + 511) / 512;
    fill_kernel<<<FB, 256, 0, stream>>>(src, dst, rl, bsum, epos, esrc, E4, E);

    // K4: softmax + weighted aggregation
    aggregate<<<N, 64, 0, stream>>>(rl, bsum, esrc, el, er, featb, bias, out, N);
}

// Round 10
// 156.596 us; speedup vs baseline: 1.0366x; 1.0366x over previous
//
#include <hip/hip_runtime.h>

#define IN_DIM 256
#define HD 256        // H*D
#define NHEAD 4
#define BM 128        // rows per block in gemm

typedef __attribute__((ext_vector_type(8))) short short8;
typedef __attribute__((ext_vector_type(4))) float f32x4;

__device__ __forceinline__ float bf2f(ushort u) {
    unsigned x = ((unsigned)u) << 16;
    float f;
    __builtin_memcpy(&f, &x, 4);
    return f;
}
__device__ __forceinline__ ushort f2bf(float f) {
    unsigned x;
    __builtin_memcpy(&x, &f, 4);
    unsigned r = (x + 0x7FFFu + ((x >> 16) & 1u)) >> 16;   // RNE
    return (ushort)r;
}
__device__ __forceinline__ short8 cvt8(float4 x, float4 y) {
    short8 a;
    a[0] = (short)f2bf(x.x); a[1] = (short)f2bf(x.y);
    a[2] = (short)f2bf(x.z); a[3] = (short)f2bf(x.w);
    a[4] = (short)f2bf(y.x); a[5] = (short)f2bf(y.y);
    a[6] = (short)f2bf(y.z); a[7] = (short)f2bf(y.w);
    return a;
}

// ---------------------------------------------------------------- fallback (ws-too-small tripwire)
__global__ void fill_one(float* __restrict__ out, int n) {
    int i = blockIdx.x * 256 + threadIdx.x;
    if (i < n) out[i] = 1.0f;
}

// ---------------------------------------------------------------- K0: WT build + cnt/done zero
__global__ void conv_w_zero(const float* __restrict__ W, ushort* __restrict__ WT,
                            int* __restrict__ cnt, int* __restrict__ donecnt, int n) {
    int idx = blockIdx.x * 256 + threadIdx.x;   // 65536 threads
    int k = idx >> 8, c = idx & 255;
    WT[c * 256 + k] = f2bf(W[idx]);
    for (int i = idx; i < n; i += 65536) cnt[i] = 0;
    if (idx == 0) *donecnt = 0;
}

// ---------------------------------------------------------------- K1: FAT kernel = gemm (blocks < gb) + hist (blocks >= gb)
// (round-8 structure: dedicated hist blocks backfill CU slots as gemm blocks retire)
// gemm: feat = h @ W (LDS-staged, BM=128) + fused el/er
//   MFMA 16x16x32 bf16 fragment layout (m92-verified):
//   A lane l -> row l&15, k=(l>>4)*8..+7 ; B lane l -> col l&15, same k packing
//   D lane l -> col l&15, row (l>>4)*4 + reg
__global__ __launch_bounds__(256, 2) void gemm_hist(const float* __restrict__ h,
                                                    const short* __restrict__ WT,
                                                    ushort* __restrict__ featb,
                                                    float* __restrict__ el,
                                                    float* __restrict__ er,
                                                    const float* __restrict__ attn_l,
                                                    const float* __restrict__ attn_r,
                                                    const int* __restrict__ dst,
                                                    int* __restrict__ cnt,
                                                    int* __restrict__ epos,
                                                    int gb, int n, int e) {
    if (blockIdx.x >= gb) {
        // ---------------- hist path ----------------
        int i = (blockIdx.x - gb) * 256 + threadIdx.x;
        int base = i * 4;
        if (base + 3 < e) {
            int4 d4 = *(const int4*)(dst + base);
            int4 p4;
            p4.x = atomicAdd(&cnt[d4.x], 1);
            p4.y = atomicAdd(&cnt[d4.y], 1);
            p4.z = atomicAdd(&cnt[d4.z], 1);
            p4.w = atomicAdd(&cnt[d4.w], 1);
            *(int4*)(epos + base) = p4;
        } else {
            for (int q = base; q < e; ++q) epos[q] = atomicAdd(&cnt[dst[q]], 1);
        }
        return;
    }
    // ---------------- gemm path ----------------
    __shared__ __align__(16) ushort blds[2][8192];   // 2 x 16 KB
    int t = threadIdx.x;
    int w = t >> 6, l = t & 63;
    int c15 = l & 15, g = l >> 4;
    int blockBase = blockIdx.x * BM;
    int row0 = blockBase + w * 32 + c15;
    int rA0 = row0 < n ? row0 : n - 1;
    int rA1 = (row0 + 16) < n ? (row0 + 16) : n - 1;
    const float* hA0 = h + (size_t)rA0 * 256 + g * 8;
    const float* hA1 = h + (size_t)rA1 * 256 + g * 8;

    f32x4 acc[2][16];
#pragma unroll
    for (int af = 0; af < 2; ++af)
#pragma unroll
        for (int ct = 0; ct < 16; ++ct) acc[af][ct] = (f32x4)(0.0f);

    short8 st[4];
    int sc[4], sb[4];
#pragma unroll
    for (int p = 0; p < 4; ++p) {
        int q = t + p * 256;
        sc[p] = q >> 2;
        int gg = q & 3;
        sb[p] = ((sc[p] * 64 + gg * 16) ^ ((sc[p] & 7) << 4));
    }

#pragma unroll
    for (int p = 0; p < 4; ++p)
        st[p] = *(const short8*)(WT + sc[p] * 256 + ((t + p * 256) & 3) * 8);
#pragma unroll
    for (int p = 0; p < 4; ++p)
        *(short8*)((char*)blds[0] + sb[p]) = st[p];
    __syncthreads();

    for (int kk = 0; kk < 8; ++kk) {
        int buf = kk & 1;
        if (kk < 7) {
#pragma unroll
            for (int p = 0; p < 4; ++p)
                st[p] = *(const short8*)(WT + sc[p] * 256 + (kk + 1) * 32 + ((t + p * 256) & 3) * 8);
        }
        float4 x0 = *(const float4*)(hA0 + kk * 32);
        float4 y0 = *(const float4*)(hA0 + kk * 32 + 4);
        float4 x1 = *(const float4*)(hA1 + kk * 32);
        float4 y1 = *(const float4*)(hA1 + kk * 32 + 4);
        short8 a0 = cvt8(x0, y0);
        short8 a1 = cvt8(x1, y1);
        const char* bb = (const char*)blds[buf];
#pragma unroll
        for (int ct = 0; ct < 16; ++ct) {
            int c = ct * 16 + c15;
            short8 bv = *(const short8*)(bb + ((c * 64 + g * 16) ^ ((c & 7) << 4)));
            acc[0][ct] = __builtin_amdgcn_mfma_f32_16x16x32_bf16(a0, bv, acc[0][ct], 0, 0, 0);
            acc[1][ct] = __builtin_amdgcn_mfma_f32_16x16x32_bf16(a1, bv, acc[1][ct], 0, 0, 0);
        }
        if (kk < 7) {
#pragma unroll
            for (int p = 0; p < 4; ++p)
                *(short8*)((char*)blds[buf ^ 1] + sb[p]) = st[p];
        }
        __syncthreads();
    }

    float alv[16], arv[16];
#pragma unroll
    for (int ct = 0; ct < 16; ++ct) {
        alv[ct] = attn_l[ct * 16 + c15];
        arv[ct] = attn_r[ct * 16 + c15];
    }

#pragma unroll
    for (int af = 0; af < 2; ++af) {
        int rowb = blockBase + w * 32 + af * 16 + g * 4;
#pragma unroll
        for (int r = 0; r < 4; ++r) {
            int row = rowb + r;
            if (row < n) {
#pragma unroll
                for (int ct = 0; ct < 16; ++ct)
                    featb[(size_t)row * 256 + ct * 16 + c15] = f2bf(acc[af][ct][r]);
            }
            float pl[4] = {0.f, 0.f, 0.f, 0.f}, pr[4] = {0.f, 0.f, 0.f, 0.f};
#pragma unroll
            for (int ct = 0; ct < 16; ++ct) {
                pl[ct >> 2] += acc[af][ct][r] * alv[ct];
                pr[ct >> 2] += acc[af][ct][r] * arv[ct];
            }
#pragma unroll
            for (int m = 1; m < 16; m <<= 1) {
#pragma unroll
                for (int hh = 0; hh < 4; ++hh) {
                    pl[hh] += __shfl_xor(pl[hh], m, 64);
                    pr[hh] += __shfl_xor(pr[hh], m, 64);
                }
            }
            if (row < n) {
                if (c15 < 4)       el[row * 4 + c15]       = pl[c15];
                else if (c15 < 8)  er[row * 4 + (c15 - 4)] = pr[c15 - 4];
            }
        }
    }
}

// ---------------------------------------------------------------- K2: fused two-level scan (last-block pattern)
__global__ __launch_bounds__(1024) void scan_fused(const int* __restrict__ cnt,
                                                   int* __restrict__ rl,
                                                   int* __restrict__ bsum,
                                                   int* __restrict__ donecnt,
                                                   int n, int nb) {
    __shared__ int wsums[16];
    __shared__ int isLast;
    int t = threadIdx.x, lane = t & 63, wid = t >> 6;
    int i = blockIdx.x * 1024 + t;
    int x = (i < n) ? cnt[i] : 0;
    int s = x;
#pragma unroll
    for (int off = 1; off < 64; off <<= 1) {
        int v = __shfl_up(s, off, 64);
        if (lane >= off) s += v;
    }
    if (lane == 63) wsums[wid] = s;
    __syncthreads();
    if (wid == 0) {
        int ws = (lane < 16) ? wsums[lane] : 0;
#pragma unroll
        for (int off = 1; off < 16; off <<= 1) {
            int v = __shfl_up(ws, off, 64);
            if (lane >= off) ws += v;
        }
        if (lane < 16) wsums[lane] = ws;
    }
    __syncthreads();
    int woff = (wid > 0) ? wsums[wid - 1] : 0;
    if (i <= n) rl[i] = woff + s - x;
    if (t == 1023) bsum[blockIdx.x] = wsums[15];

    // last block to finish scans bsum (exclusive, in place)
    __threadfence();
    if (t == 0) {
        int prev = atomicAdd(donecnt, 1);
        isLast = (prev == gridDim.x - 1) ? 1 : 0;
    }
    __syncthreads();
    if (!isLast) return;
    __threadfence();   // acquire: see all blocks' bsum writes
    int carry = 0;
    for (int base = 0; base < nb; base += 1024) {
        __syncthreads();
        int ii = base + t;
        int xx = (ii < nb) ? bsum[ii] : 0;
        int ss = xx;
#pragma unroll
        for (int off = 1; off < 64; off <<= 1) {
            int v = __shfl_up(ss, off, 64);
            if (lane >= off) ss += v;
        }
        if (lane == 63) wsums[wid] = ss;
        __syncthreads();
        if (wid == 0) {
            int ws = (lane < 16) ? wsums[lane] : 0;
#pragma unroll
            for (int off = 1; off < 16; off <<= 1) {
                int v = __shfl_up(ws, off, 64);
                if (lane >= off) ws += v;
            }
            if (lane < 16) wsums[lane] = ws;
        }
        __syncthreads();
        int woff2 = (wid > 0) ? wsums[wid - 1] : 0;
        if (ii < nb) bsum[ii] = carry + woff2 + ss - xx;
        int tot = wsums[15];
        carry += tot;
    }
}

// ---------------------------------------------------------------- K3: CSR fill — no atomic, 4 edges/thread (round-8 grid)
__global__ void fill_kernel(const int* __restrict__ src, const int* __restrict__ dst,
                            const int* __restrict__ rl, const int* __restrict__ boffs,
                            const int* __restrict__ epos,
                            int* __restrict__ esrc, int e) {
    int i = blockIdx.x * 256 + threadIdx.x;
    int base = i * 4;
    if (base + 3 < e) {
        int4 d4 = *(const int4*)(dst + base);
        int4 s4 = *(const int4*)(src + base);
        int4 p4 = *(const int4*)(epos + base);
        int pos0 = boffs[d4.x >> 10] + rl[d4.x] + p4.x;
        int pos1 = boffs[d4.y >> 10] + rl[d4.y] + p4.y;
        int pos2 = boffs[d4.z >> 10] + rl[d4.z] + p4.z;
        int pos3 = boffs[d4.w >> 10] + rl[d4.w] + p4.w;
        if (pos0 >= 0 && pos0 < e) esrc[pos0] = s4.x;
        if (pos1 >= 0 && pos1 < e) esrc[pos1] = s4.y;
        if (pos2 >= 0 && pos2 < e) esrc[pos2] = s4.z;
        if (pos3 >= 0 && pos3 < e) esrc[pos3] = s4.w;
    } else {
        for (int q = base; q < e; ++q) {
            int d = dst[q];
            int pos = boffs[d >> 10] + rl[d] + epos[q];
            if (pos >= 0 && pos < e) esrc[pos] = src[q];
        }
    }
}

// ---------------------------------------------------------------- K4: per-dst aggregate, 1 wave/node (at delivered-BW ceiling)
__global__ __launch_bounds__(64) void aggregate(const int* __restrict__ rl,
                                                const int* __restrict__ boffs,
                                                const int* __restrict__ esrc,
                                                const float* __restrict__ el,
                                                const float* __restrict__ er,
                                                const ushort* __restrict__ featb,
                                                const float* __restrict__ bias,
                                                float* __restrict__ out, int n) {
    __shared__ int sbuf[64];
    __shared__ float wbuf[64][4];
    int node = blockIdx.x;
    int l = threadIdx.x;
    int hh = l >> 4;
    int beg = boffs[node >> 10] + rl[node];
    int end = boffs[(node + 1) >> 10] + rl[node + 1];
    float4 bv = *(const float4*)(bias + l * 4);
    float* op = out + (size_t)node * 256 + l * 4;
    if (beg >= end) {
        float4 v;
        v.x = bv.x > 0.f ? bv.x : 0.01f * bv.x;
        v.y = bv.y > 0.f ? bv.y : 0.01f * bv.y;
        v.z = bv.z > 0.f ? bv.z : 0.01f * bv.z;
        v.w = bv.w > 0.f ? bv.w : 0.01f * bv.w;
        *(float4*)op = v;
        return;
    }
    float4 r4 = *(const float4*)(er + (size_t)node * 4);
    float ax = 0.f, ay = 0.f, az = 0.f, aw = 0.f, s = 0.f;
    for (int cb = beg; cb < end; cb += 64) {
        int cn = min(64, end - cb);
        __syncthreads();
        if (l < cn) {
            int sv = esrc[cb + l];
            sv = (sv >= 0 && sv < n) ? sv : 0;   // poison-proof
            sbuf[l] = sv;
            float4 l4 = *(const float4*)(el + (size_t)sv * 4);
            float e0 = l4.x + r4.x; e0 = e0 > 0.f ? e0 : 0.2f * e0;
            float e1 = l4.y + r4.y; e1 = e1 > 0.f ? e1 : 0.2f * e1;
            float e2 = l4.z + r4.z; e2 = e2 > 0.f ? e2 : 0.2f * e2;
            float e3 = l4.w + r4.w; e3 = e3 > 0.f ? e3 : 0.2f * e3;
            wbuf[l][0] = __expf(fminf(e0, 60.f));
            wbuf[l][1] = __expf(fminf(e1, 60.f));
            wbuf[l][2] = __expf(fminf(e2, 60.f));
            wbuf[l][3] = __expf(fminf(e3, 60.f));
        }
        __syncthreads();
#pragma unroll 4
        for (int j = 0; j < cn; ++j) {
            int sid = sbuf[j];
            float wgt = wbuf[j][hh];
            ushort4 f4 = *(const ushort4*)(featb + (size_t)sid * 256 + l * 4);
            ax += wgt * bf2f(f4.x);
            ay += wgt * bf2f(f4.y);
            az += wgt * bf2f(f4.z);
            aw += wgt * bf2f(f4.w);
            s += wgt;
        }
    }
    float inv = 1.f / fmaxf(s, 1e-9f);
    float4 v;
    v.x = ax * inv + bv.x; v.x = v.x > 0.f ? v.x : 0.01f * v.x;
    v.y = ay * inv + bv.y; v.y = v.y > 0.f ? v.y : 0.01f * v.y;
    v.z = az * inv + bv.z; v.z = v.z > 0.f ? v.z : 0.01f * v.z;
    v.w = aw * inv + bv.w; v.w = v.w > 0.f ? v.w : 0.01f * v.w;
    *(float4*)op = v;
}

// ----------------------------------------------------------------
extern "C" void kernel_launch(void* const* d_in, const int* in_sizes, int n_in,
                              void* d_out, int out_size, void* d_ws, size_t ws_size,
                              hipStream_t stream) {
    const float* h      = (const float*)d_in[0];
    const int*   src    = (const int*)d_in[1];
    const int*   dst    = (const int*)d_in[2];
    const float* W      = (const float*)d_in[3];
    const float* attn_l = (const float*)d_in[4];
    const float* attn_r = (const float*)d_in[5];
    const float* bias   = (const float*)d_in[6];
    float* out = (float*)d_out;

    int N = in_sizes[0] / IN_DIM;
    int E = in_sizes[1];
    int NB = (N + 1 + 1023) / 1024;

    auto al = [](size_t x) { return (x + 255) & ~(size_t)255; };
    char* ws = (char*)d_ws;
    size_t o = 0;
    ushort* featb = (ushort*)(ws + o); o += al((size_t)N * HD * 2);
    float*  el    = (float*)(ws + o);  o += al((size_t)N * NHEAD * 4);
    float*  er    = (float*)(ws + o);  o += al((size_t)N * NHEAD * 4);
    int*    rl    = (int*)(ws + o);    o += al((size_t)(N + 1) * 4);
    int*    cnt   = (int*)(ws + o);    o += al((size_t)N * 4);
    int*    bsum  = (int*)(ws + o);    o += al((size_t)NB * 4);
    int*    done  = (int*)(ws + o);    o += al(4);
    int*    esrc  = (int*)(ws + o);    o += al((size_t)E * 4);
    int*    epos  = (int*)(ws + o);    o += al((size_t)E * 4);
    ushort* WT    = (ushort*)(ws + o); o += al((size_t)IN_DIM * HD * 2);
    (void)n_in;

    if (ws_size < o) {
        fill_one<<<(out_size + 255) / 256, 256, 0, stream>>>(out, out_size);
        return;
    }

    // K0: WT build + cnt/done zero
    conv_w_zero<<<(IN_DIM * HD) / 256, 256, 0, stream>>>(W, WT, cnt, done, N);

    // K1: fat kernel — gemm blocks + dedicated hist blocks (round-8 structure)
    int GB = (N + BM - 1) / BM;
    int HB = ((E + 3) / 4 + 255) / 256;
    gemm_hist<<<GB + HB, 256, 0, stream>>>(h, (const short*)WT, featb, el, er,
                                           attn_l, attn_r, dst, cnt, epos, GB, N, E);

    // K2: fused two-level scan (single launch)
    scan_fused<<<NB, 1024, 0, stream>>>(cnt, rl, bsum, done, N, NB);

    // K3: CSR fill (no atomics), 1 granule/thread (round-8 grid)
    fill_kernel<<<((E + 3) / 4 + 255) / 256, 256, 0, stream>>>(src, dst, rl, bsum, epos, esrc, E);

    // K4: softmax + weighted aggregation
    aggregate<<<N, 64, 0, stream>>>(rl, bsum, esrc, el, er, featb, bias, out, N);
}

// Round 11
// 138.911 us; speedup vs baseline: 1.1686x; 1.1273x over previous
//
#include <hip/hip_runtime.h>

#define IN_DIM 256
#define HD 256        // H*D
#define NHEAD 4
#define BM 128        // rows per block in gemm

typedef __attribute__((ext_vector_type(8))) short short8;
typedef __attribute__((ext_vector_type(4))) float f32x4;

__device__ __forceinline__ float bf2f(ushort u) {
    unsigned x = ((unsigned)u) << 16;
    float f;
    __builtin_memcpy(&f, &x, 4);
    return f;
}
__device__ __forceinline__ ushort f2bf(float f) {
    unsigned x;
    __builtin_memcpy(&x, &f, 4);
    unsigned r = (x + 0x7FFFu + ((x >> 16) & 1u)) >> 16;   // RNE
    return (ushort)r;
}
__device__ __forceinline__ short8 cvt8(float4 x, float4 y) {
    short8 a;
    a[0] = (short)f2bf(x.x); a[1] = (short)f2bf(x.y);
    a[2] = (short)f2bf(x.z); a[3] = (short)f2bf(x.w);
    a[4] = (short)f2bf(y.x); a[5] = (short)f2bf(y.y);
    a[6] = (short)f2bf(y.z); a[7] = (short)f2bf(y.w);
    return a;
}

// ---------------------------------------------------------------- fallback (ws-too-small tripwire)
__global__ void fill_one(float* __restrict__ out, int n) {
    int i = blockIdx.x * 256 + threadIdx.x;
    if (i < n) out[i] = 1.0f;
}

// ---------------------------------------------------------------- K0: WT build + cnt zero (fused, independent writes)
__global__ void conv_w_zero(const float* __restrict__ W, ushort* __restrict__ WT,
                            int* __restrict__ cnt, int n) {
    int idx = blockIdx.x * 256 + threadIdx.x;   // 65536 threads
    int k = idx >> 8, c = idx & 255;
    WT[c * 256 + k] = f2bf(W[idx]);
    for (int i = idx; i < n; i += 65536) cnt[i] = 0;
}

// ---------------------------------------------------------------- K1: FAT kernel = gemm (blocks < gb) + hist (blocks >= gb)
// gemm: feat = h @ W (LDS-staged, BM=128) + fused el/er
//   MFMA 16x16x32 bf16 fragment layout (m92-verified):
//   A lane l -> row l&15, k=(l>>4)*8..+7 ; B lane l -> col l&15, same k packing
//   D lane l -> col l&15, row (l>>4)*4 + reg
// hist: epos[i] = atomicAdd(cnt[dst[i]], 1), 4 edges/thread
__global__ __launch_bounds__(256, 2) void gemm_hist(const float* __restrict__ h,
                                                    const short* __restrict__ WT,
                                                    ushort* __restrict__ featb,
                                                    float* __restrict__ el,
                                                    float* __restrict__ er,
                                                    const float* __restrict__ attn_l,
                                                    const float* __restrict__ attn_r,
                                                    const int* __restrict__ dst,
                                                    int* __restrict__ cnt,
                                                    int* __restrict__ epos,
                                                    int gb, int n, int e) {
    if (blockIdx.x >= gb) {
        // ---------------- hist path ----------------
        int i = (blockIdx.x - gb) * 256 + threadIdx.x;
        int base = i * 4;
        if (base + 3 < e) {
            int4 d4 = *(const int4*)(dst + base);
            int4 p4;
            p4.x = atomicAdd(&cnt[d4.x], 1);
            p4.y = atomicAdd(&cnt[d4.y], 1);
            p4.z = atomicAdd(&cnt[d4.z], 1);
            p4.w = atomicAdd(&cnt[d4.w], 1);
            *(int4*)(epos + base) = p4;
        } else {
            for (int q = base; q < e; ++q) epos[q] = atomicAdd(&cnt[dst[q]], 1);
        }
        return;
    }
    // ---------------- gemm path ----------------
    __shared__ __align__(16) ushort blds[2][8192];   // 2 x 16 KB
    int t = threadIdx.x;
    int w = t >> 6, l = t & 63;
    int c15 = l & 15, g = l >> 4;
    int blockBase = blockIdx.x * BM;
    int row0 = blockBase + w * 32 + c15;
    int rA0 = row0 < n ? row0 : n - 1;
    int rA1 = (row0 + 16) < n ? (row0 + 16) : n - 1;
    const float* hA0 = h + (size_t)rA0 * 256 + g * 8;
    const float* hA1 = h + (size_t)rA1 * 256 + g * 8;

    f32x4 acc[2][16];
#pragma unroll
    for (int af = 0; af < 2; ++af)
#pragma unroll
        for (int ct = 0; ct < 16; ++ct) acc[af][ct] = (f32x4)(0.0f);

    short8 st[4];
    int sc[4], sb[4];
#pragma unroll
    for (int p = 0; p < 4; ++p) {
        int q = t + p * 256;
        sc[p] = q >> 2;
        int gg = q & 3;
        sb[p] = ((sc[p] * 64 + gg * 16) ^ ((sc[p] & 7) << 4));
    }

#pragma unroll
    for (int p = 0; p < 4; ++p)
        st[p] = *(const short8*)(WT + sc[p] * 256 + ((t + p * 256) & 3) * 8);
#pragma unroll
    for (int p = 0; p < 4; ++p)
        *(short8*)((char*)blds[0] + sb[p]) = st[p];
    __syncthreads();

    for (int kk = 0; kk < 8; ++kk) {
        int buf = kk & 1;
        if (kk < 7) {
#pragma unroll
            for (int p = 0; p < 4; ++p)
                st[p] = *(const short8*)(WT + sc[p] * 256 + (kk + 1) * 32 + ((t + p * 256) & 3) * 8);
        }
        float4 x0 = *(const float4*)(hA0 + kk * 32);
        float4 y0 = *(const float4*)(hA0 + kk * 32 + 4);
        float4 x1 = *(const float4*)(hA1 + kk * 32);
        float4 y1 = *(const float4*)(hA1 + kk * 32 + 4);
        short8 a0 = cvt8(x0, y0);
        short8 a1 = cvt8(x1, y1);
        const char* bb = (const char*)blds[buf];
#pragma unroll
        for (int ct = 0; ct < 16; ++ct) {
            int c = ct * 16 + c15;
            short8 bv = *(const short8*)(bb + ((c * 64 + g * 16) ^ ((c & 7) << 4)));
            acc[0][ct] = __builtin_amdgcn_mfma_f32_16x16x32_bf16(a0, bv, acc[0][ct], 0, 0, 0);
            acc[1][ct] = __builtin_amdgcn_mfma_f32_16x16x32_bf16(a1, bv, acc[1][ct], 0, 0, 0);
        }
        if (kk < 7) {
#pragma unroll
            for (int p = 0; p < 4; ++p)
                *(short8*)((char*)blds[buf ^ 1] + sb[p]) = st[p];
        }
        __syncthreads();
    }

    float alv[16], arv[16];
#pragma unroll
    for (int ct = 0; ct < 16; ++ct) {
        alv[ct] = attn_l[ct * 16 + c15];
        arv[ct] = attn_r[ct * 16 + c15];
    }

#pragma unroll
    for (int af = 0; af < 2; ++af) {
        int rowb = blockBase + w * 32 + af * 16 + g * 4;
#pragma unroll
        for (int r = 0; r < 4; ++r) {
            int row = rowb + r;
            if (row < n) {
#pragma unroll
                for (int ct = 0; ct < 16; ++ct)
                    featb[(size_t)row * 256 + ct * 16 + c15] = f2bf(acc[af][ct][r]);
            }
            float pl[4] = {0.f, 0.f, 0.f, 0.f}, pr[4] = {0.f, 0.f, 0.f, 0.f};
#pragma unroll
            for (int ct = 0; ct < 16; ++ct) {
                pl[ct >> 2] += acc[af][ct][r] * alv[ct];
                pr[ct >> 2] += acc[af][ct][r] * arv[ct];
            }
#pragma unroll
            for (int m = 1; m < 16; m <<= 1) {
#pragma unroll
                for (int hh = 0; hh < 4; ++hh) {
                    pl[hh] += __shfl_xor(pl[hh], m, 64);
                    pr[hh] += __shfl_xor(pr[hh], m, 64);
                }
            }
            if (row < n) {
                if (c15 < 4)       el[row * 4 + c15]       = pl[c15];
                else if (c15 < 8)  er[row * 4 + (c15 - 4)] = pr[c15 - 4];
            }
        }
    }
}

// ---------------------------------------------------------------- K2a: block-local exclusive scan (tiles of 1024)
__global__ __launch_bounds__(1024) void scan_local(const int* __restrict__ cnt,
                                                   int* __restrict__ rl,
                                                   int* __restrict__ bsum, int n) {
    __shared__ int wsums[16];
    int t = threadIdx.x, lane = t & 63, wid = t >> 6;
    int i = blockIdx.x * 1024 + t;
    int x = (i < n) ? cnt[i] : 0;
    int s = x;
#pragma unroll
    for (int off = 1; off < 64; off <<= 1) {
        int v = __shfl_up(s, off, 64);
        if (lane >= off) s += v;
    }
    if (lane == 63) wsums[wid] = s;
    __syncthreads();
    if (wid == 0) {
        int ws = (lane < 16) ? wsums[lane] : 0;
#pragma unroll
        for (int off = 1; off < 16; off <<= 1) {
            int v = __shfl_up(ws, off, 64);
            if (lane >= off) ws += v;
        }
        if (lane < 16) wsums[lane] = ws;
    }
    __syncthreads();
    int woff = (wid > 0) ? wsums[wid - 1] : 0;
    if (i <= n) rl[i] = woff + s - x;
    if (t == 1023) bsum[blockIdx.x] = wsums[15];
}

// ---------------------------------------------------------------- K2b: exclusive scan of block sums (in place)
__global__ __launch_bounds__(1024) void scan_bsum(int* __restrict__ bsum, int nb) {
    __shared__ int wsums[16];
    int t = threadIdx.x, lane = t & 63, wid = t >> 6;
    int x = (t < nb) ? bsum[t] : 0;
    int s = x;
#pragma unroll
    for (int off = 1; off < 64; off <<= 1) {
        int v = __shfl_up(s, off, 64);
        if (lane >= off) s += v;
    }
    if (lane == 63) wsums[wid] = s;
    __syncthreads();
    if (wid == 0) {
        int ws = (lane < 16) ? wsums[lane] : 0;
#pragma unroll
        for (int off = 1; off < 16; off <<= 1) {
            int v = __shfl_up(ws, off, 64);
            if (lane >= off) ws += v;
        }
        if (lane < 16) wsums[lane] = ws;
    }
    __syncthreads();
    int woff = (wid > 0) ? wsums[wid - 1] : 0;
    if (t < nb) bsum[t] = woff + s - x;
}

// ---------------------------------------------------------------- K3: CSR fill — no atomic, 4 edges/thread
__global__ void fill_kernel(const int* __restrict__ src, const int* __restrict__ dst,
                            const int* __restrict__ rl, const int* __restrict__ boffs,
                            const int* __restrict__ epos,
                            int* __restrict__ esrc, int e) {
    int i = blockIdx.x * 256 + threadIdx.x;
    int base = i * 4;
    if (base + 3 < e) {
        int4 d4 = *(const int4*)(dst + base);
        int4 s4 = *(const int4*)(src + base);
        int4 p4 = *(const int4*)(epos + base);
        int pos0 = boffs[d4.x >> 10] + rl[d4.x] + p4.x;
        int pos1 = boffs[d4.y >> 10] + rl[d4.y] + p4.y;
        int pos2 = boffs[d4.z >> 10] + rl[d4.z] + p4.z;
        int pos3 = boffs[d4.w >> 10] + rl[d4.w] + p4.w;
        if (pos0 >= 0 && pos0 < e) esrc[pos0] = s4.x;
        if (pos1 >= 0 && pos1 < e) esrc[pos1] = s4.y;
        if (pos2 >= 0 && pos2 < e) esrc[pos2] = s4.z;
        if (pos3 >= 0 && pos3 < e) esrc[pos3] = s4.w;
    } else {
        for (int q = base; q < e; ++q) {
            int d = dst[q];
            int pos = boffs[d >> 10] + rl[d] + epos[q];
            if (pos >= 0 && pos < e) esrc[pos] = src[q];
        }
    }
}

// ---------------------------------------------------------------- K4: per-dst aggregate, 1 wave/node
__global__ __launch_bounds__(64) void aggregate(const int* __restrict__ rl,
                                                const int* __restrict__ boffs,
                                                const int* __restrict__ esrc,
                                                const float* __restrict__ el,
                                                const float* __restrict__ er,
                                                const ushort* __restrict__ featb,
                                                const float* __restrict__ bias,
                                                float* __restrict__ out, int n) {
    __shared__ int sbuf[64];
    __shared__ float wbuf[64][4];
    int node = blockIdx.x;
    int l = threadIdx.x;
    int hh = l >> 4;
    int beg = boffs[node >> 10] + rl[node];
    int end = boffs[(node + 1) >> 10] + rl[node + 1];
    float4 bv = *(const float4*)(bias + l * 4);
    float* op = out + (size_t)node * 256 + l * 4;
    if (beg >= end) {
        float4 v;
        v.x = bv.x > 0.f ? bv.x : 0.01f * bv.x;
        v.y = bv.y > 0.f ? bv.y : 0.01f * bv.y;
        v.z = bv.z > 0.f ? bv.z : 0.01f * bv.z;
        v.w = bv.w > 0.f ? bv.w : 0.01f * bv.w;
        *(float4*)op = v;
        return;
    }
    float4 r4 = *(const float4*)(er + (size_t)node * 4);
    float ax = 0.f, ay = 0.f, az = 0.f, aw = 0.f, s = 0.f;
    for (int cb = beg; cb < end; cb += 64) {
        int cn = min(64, end - cb);
        __syncthreads();
        if (l < cn) {
            int sv = esrc[cb + l];
            sv = (sv >= 0 && sv < n) ? sv : 0;   // poison-proof
            sbuf[l] = sv;
            float4 l4 = *(const float4*)(el + (size_t)sv * 4);
            float e0 = l4.x + r4.x; e0 = e0 > 0.f ? e0 : 0.2f * e0;
            float e1 = l4.y + r4.y; e1 = e1 > 0.f ? e1 : 0.2f * e1;
            float e2 = l4.z + r4.z; e2 = e2 > 0.f ? e2 : 0.2f * e2;
            float e3 = l4.w + r4.w; e3 = e3 > 0.f ? e3 : 0.2f * e3;
            wbuf[l][0] = __expf(fminf(e0, 60.f));
            wbuf[l][1] = __expf(fminf(e1, 60.f));
            wbuf[l][2] = __expf(fminf(e2, 60.f));
            wbuf[l][3] = __expf(fminf(e3, 60.f));
        }
        __syncthreads();
#pragma unroll 4
        for (int j = 0; j < cn; ++j) {
            int sid = sbuf[j];
            float wgt = wbuf[j][hh];
            ushort4 f4 = *(const ushort4*)(featb + (size_t)sid * 256 + l * 4);
            ax += wgt * bf2f(f4.x);
            ay += wgt * bf2f(f4.y);
            az += wgt * bf2f(f4.z);
            aw += wgt * bf2f(f4.w);
            s += wgt;
        }
    }
    float inv = 1.f / fmaxf(s, 1e-9f);
    float4 v;
    v.x = ax * inv + bv.x; v.x = v.x > 0.f ? v.x : 0.01f * v.x;
    v.y = ay * inv + bv.y; v.y = v.y > 0.f ? v.y : 0.01f * v.y;
    v.z = az * inv + bv.z; v.z = v.z > 0.f ? v.z : 0.01f * v.z;
    v.w = aw * inv + bv.w; v.w = v.w > 0.f ? v.w : 0.01f * v.w;
    *(float4*)op = v;
}

// ----------------------------------------------------------------
extern "C" void kernel_launch(void* const* d_in, const int* in_sizes, int n_in,
                              void* d_out, int out_size, void* d_ws, size_t ws_size,
                              hipStream_t stream) {
    const float* h      = (const float*)d_in[0];
    const int*   src    = (const int*)d_in[1];
    const int*   dst    = (const int*)d_in[2];
    const float* W      = (const float*)d_in[3];
    const float* attn_l = (const float*)d_in[4];
    const float* attn_r = (const float*)d_in[5];
    const float* bias   = (const float*)d_in[6];
    float* out = (float*)d_out;

    int N = in_sizes[0] / IN_DIM;
    int E = in_sizes[1];
    int NB = (N + 1 + 1023) / 1024;

    auto al = [](size_t x) { return (x + 255) & ~(size_t)255; };
    char* ws = (char*)d_ws;
    size_t o = 0;
    ushort* featb = (ushort*)(ws + o); o += al((size_t)N * HD * 2);
    float*  el    = (float*)(ws + o);  o += al((size_t)N * NHEAD * 4);
    float*  er    = (float*)(ws + o);  o += al((size_t)N * NHEAD * 4);
    int*    rl    = (int*)(ws + o);    o += al((size_t)(N + 1) * 4);
    int*    cnt   = (int*)(ws + o);    o += al((size_t)N * 4);
    int*    bsum  = (int*)(ws + o);    o += al((size_t)NB * 4);
    int*    esrc  = (int*)(ws + o);    o += al((size_t)E * 4);
    int*    epos  = (int*)(ws + o);    o += al((size_t)E * 4);
    ushort* WT    = (ushort*)(ws + o); o += al((size_t)IN_DIM * HD * 2);
    (void)n_in;

    if (ws_size < o) {
        fill_one<<<(out_size + 255) / 256, 256, 0, stream>>>(out, out_size);
        return;
    }

    // K0: WT build + cnt zero (fused)
    conv_w_zero<<<(IN_DIM * HD) / 256, 256, 0, stream>>>(W, WT, cnt, N);

    // K1: fat kernel — gemm blocks + hist blocks co-resident
    int GB = (N + BM - 1) / BM;
    int HB = ((E + 3) / 4 + 255) / 256;
    gemm_hist<<<GB + HB, 256, 0, stream>>>(h, (const short*)WT, featb, el, er,
                                           attn_l, attn_r, dst, cnt, epos, GB, N, E);

    // K2: two-level scan
    scan_local<<<NB, 1024, 0, stream>>>(cnt, rl, bsum, N);
    scan_bsum<<<1, 1024, 0, stream>>>(bsum, NB);

    // K3: CSR fill (no atomics)
    fill_kernel<<<((E + 3) / 4 + 255) / 256, 256, 0, stream>>>(src, dst, rl, bsum, epos, esrc, E);

    // K4: softmax + weighted aggregation
    aggregate<<<N, 64, 0, stream>>>(rl, bsum, esrc, el, er, featb, bias, out, N);
}